// Round 1
// baseline (1201.016 us; speedup 1.0000x reference)
//
#include <hip/hip_runtime.h>
#include <hip/hip_bf16.h>

typedef unsigned short u16;
typedef unsigned int   u32;
typedef __attribute__((ext_vector_type(8))) short short8;   // 8 bf16 (4 VGPRs)
typedef __attribute__((ext_vector_type(4))) float floatx4;  // MFMA acc

#define T_DIM 4096
#define D_DIM 2048
#define H_DIM 256
#define M_DIM 16384   // B*T
#define NFLAT 8192    // D*W

__device__ __forceinline__ u16 f2bf(float f) {
  union { float f; u32 u; } c; c.f = f;
  u32 x = c.u;
  x += 0x7FFFu + ((x >> 16) & 1u);   // RNE
  return (u16)(x >> 16);
}
__device__ __forceinline__ float bf2f(u16 u) {
  union { float f; u32 u; } c; c.u = ((u32)u) << 16; return c.f;
}

// ---------------- transpose + fp32->bf16 convert: src[R][C] -> dst[C][R] ----
__global__ void __launch_bounds__(256) tr_cvt(const float* __restrict__ src,
                                              u16* __restrict__ dst, int R, int C) {
  __shared__ u16 tile[32][33];
  const int tx = threadIdx.x & 31;
  const int ty = threadIdx.x >> 5;        // 0..7
  const int c0 = blockIdx.x * 32;
  const int r0 = blockIdx.y * 32;
  #pragma unroll
  for (int i = ty; i < 32; i += 8)
    tile[i][tx] = f2bf(src[(size_t)(r0 + i) * C + (c0 + tx)]);
  __syncthreads();
  #pragma unroll
  for (int i = ty; i < 32; i += 8)
    dst[(size_t)(c0 + i) * R + (r0 + tx)] = tile[tx][i];
}

// ---------------- GEMM1: h = silu(x @ w1), x fp32 (inline cvt), w1t bf16 ----
// tile 128(M) x 64(N), K=2048, BK=32. block=256thr=4 waves, wave wv: 32 rows.
__global__ void __launch_bounds__(256) gemm1_silu(const float* __restrict__ X,
                                                  const u16* __restrict__ Bt,  // w1t [256][2048]
                                                  u16* __restrict__ H) {
  __shared__ __align__(16) u16 As[128][32];
  __shared__ __align__(16) u16 Bs[64][32];
  const int tid  = threadIdx.x;
  const int lane = tid & 63, l15 = lane & 15, quad = lane >> 4;
  const int wv   = tid >> 6;                 // 0..3
  const int m0   = blockIdx.y * 128;
  const int n0   = blockIdx.x * 64;
  const int K    = D_DIM;

  floatx4 acc[2][4];
  const floatx4 zf = {0.f, 0.f, 0.f, 0.f};
  #pragma unroll
  for (int i = 0; i < 2; ++i)
    #pragma unroll
    for (int j = 0; j < 4; ++j) acc[i][j] = zf;

  for (int k0 = 0; k0 < K; k0 += 32) {
    __syncthreads();
    // stage A: fp32 -> bf16, 128x32, 4 float4 per thread
    #pragma unroll
    for (int j = 0; j < 4; ++j) {
      int idx = tid + j * 256;
      int row = idx >> 3;
      int ko  = (idx & 7) * 4;
      float4 v = *(const float4*)&X[(size_t)(m0 + row) * K + k0 + ko];
      uint2 pk;
      pk.x = (u32)f2bf(v.x) | ((u32)f2bf(v.y) << 16);
      pk.y = (u32)f2bf(v.z) | ((u32)f2bf(v.w) << 16);
      *(uint2*)&As[row][ko] = pk;
    }
    // stage B (bf16): 64x32 = 256 uint4, 1 per thread
    {
      int row = tid >> 2;
      int ko  = (tid & 3) * 8;
      *(uint4*)&Bs[row][ko] = *(const uint4*)&Bt[(size_t)(n0 + row) * K + k0 + ko];
    }
    __syncthreads();
    short8 af[2], bfr[4];
    #pragma unroll
    for (int mi = 0; mi < 2; ++mi)
      af[mi] = *(const short8*)&As[wv * 32 + mi * 16 + l15][quad * 8];
    #pragma unroll
    for (int ni = 0; ni < 4; ++ni)
      bfr[ni] = *(const short8*)&Bs[ni * 16 + l15][quad * 8];
    #pragma unroll
    for (int mi = 0; mi < 2; ++mi)
      #pragma unroll
      for (int ni = 0; ni < 4; ++ni)
        acc[mi][ni] = __builtin_amdgcn_mfma_f32_16x16x32_bf16(af[mi], bfr[ni], acc[mi][ni], 0, 0, 0);
  }
  // epilogue: silu -> bf16 h
  #pragma unroll
  for (int mi = 0; mi < 2; ++mi)
    #pragma unroll
    for (int ni = 0; ni < 4; ++ni)
      #pragma unroll
      for (int r = 0; r < 4; ++r) {
        float v = acc[mi][ni][r];
        v = v / (1.f + __expf(-v));
        int row = m0 + wv * 32 + mi * 16 + quad * 4 + r;
        int col = n0 + ni * 16 + l15;
        H[(size_t)row * H_DIM + col] = f2bf(v);
      }
}

// ---- GEMM2 fused: flat = h @ w2 + b2 ; out = silu(conv(flat, x)) ----------
// tile: 128 tokens x 32 channels (=128 contiguous flat cols, n=4d+w). K=256.
// block=256thr=4 waves in 2x2; each wave 64x64 (acc[4][4] of 16x16x32 MFMA).
__global__ void __launch_bounds__(256) gemm2_conv_silu(const u16* __restrict__ Hin,   // [M][256] bf16
                                                       const u16* __restrict__ Bt,    // w2t [8192][256] bf16
                                                       const float* __restrict__ bias,// [8192] fp32
                                                       const float* __restrict__ X,   // [M][2048] fp32
                                                       float* __restrict__ Out) {     // [M][2048] fp32
  __shared__ __align__(16) u16 As[128][32];
  __shared__ __align__(16) u16 Bs[128][32];
  __shared__ __align__(16) float fl[32][132];   // +4 pad: acc-write 2-way only

  const int tid  = threadIdx.x;
  const int lane = tid & 63, l15 = lane & 15, quad = lane >> 4;
  const int wv   = tid >> 6, wy = wv >> 1, wx = wv & 1;
  const int m0   = blockIdx.y * 128;
  const int d0   = blockIdx.x * 32;
  const int n0   = d0 * 4;               // contiguous flat-column base
  const int K    = H_DIM;                // 256

  floatx4 acc[4][4];
  const floatx4 zf = {0.f, 0.f, 0.f, 0.f};
  #pragma unroll
  for (int i = 0; i < 4; ++i)
    #pragma unroll
    for (int j = 0; j < 4; ++j) acc[i][j] = zf;

  for (int k0 = 0; k0 < K; k0 += 32) {   // 8 iterations
    __syncthreads();
    #pragma unroll
    for (int j = 0; j < 2; ++j) {        // A and B: 512 uint4 each, 2 per thread
      int idx = tid + j * 256;
      int row = idx >> 2;
      int ko  = (idx & 3) * 8;
      *(uint4*)&As[row][ko] = *(const uint4*)&Hin[(size_t)(m0 + row) * K + k0 + ko];
      *(uint4*)&Bs[row][ko] = *(const uint4*)&Bt[(size_t)(n0 + row) * K + k0 + ko];
    }
    __syncthreads();
    short8 af[4], bfr[4];
    #pragma unroll
    for (int mi = 0; mi < 4; ++mi)
      af[mi] = *(const short8*)&As[wy * 64 + mi * 16 + l15][quad * 8];
    #pragma unroll
    for (int ni = 0; ni < 4; ++ni)
      bfr[ni] = *(const short8*)&Bs[wx * 64 + ni * 16 + l15][quad * 8];
    #pragma unroll
    for (int mi = 0; mi < 4; ++mi)
      #pragma unroll
      for (int ni = 0; ni < 4; ++ni)
        acc[mi][ni] = __builtin_amdgcn_mfma_f32_16x16x32_bf16(af[mi], bfr[ni], acc[mi][ni], 0, 0, 0);
  }

  const int tbase = m0 & (T_DIM - 1);    // token offset within batch (tiles never straddle)
  const int bbase = m0 - tbase;          // b * T_DIM

  // epilogue in 4 chunks of 32 rows: acc -> LDS -> (bias, conv, silu) -> Out
  #pragma unroll 1
  for (int mi = 0; mi < 4; ++mi) {
    __syncthreads();                      // previous chunk fully read
    #pragma unroll
    for (int ni = 0; ni < 4; ++ni)
      #pragma unroll
      for (int r = 0; r < 4; ++r)
        fl[wy * 16 + quad * 4 + r][wx * 64 + ni * 16 + l15] = acc[mi][ni][r];
    __syncthreads();
    #pragma unroll
    for (int p = 0; p < 4; ++p) {
      int i    = tid + p * 256;           // 1024 outputs: 32 rows x 32 channels
      int rowc = i >> 5;                  // 0..31
      int dl   = i & 31;
      int t_local = (rowc >> 4) * 64 + mi * 16 + (rowc & 15);
      float4 pre = *(const float4*)&fl[rowc][dl * 4];
      float4 bv  = *(const float4*)&bias[(size_t)(d0 + dl) * 4];
      float c0 = pre.x + bv.x, c1 = pre.y + bv.y, c2 = pre.z + bv.z, c3 = pre.w + bv.w;
      int tb = tbase + t_local;
      const float* xcol = &X[(size_t)(bbase + tb) * D_DIM + d0 + dl];
      // out[t] = sum_w flat[t,d,w] * x[t-3+w, d]; tap w=3 hits x[t] (always valid)
      float o = c3 * xcol[0];
      float x2 = (tb >= 1) ? xcol[-(int)D_DIM]     : 0.f;
      float x1 = (tb >= 2) ? xcol[-2 * (int)D_DIM] : 0.f;
      float x0 = (tb >= 3) ? xcol[-3 * (int)D_DIM] : 0.f;
      o += c2 * x2 + c1 * x1 + c0 * x0;
      float y = o / (1.f + __expf(-o));
      Out[(size_t)(m0 + t_local) * D_DIM + d0 + dl] = y;
    }
  }
}

extern "C" void kernel_launch(void* const* d_in, const int* in_sizes, int n_in,
                              void* d_out, int out_size, void* d_ws, size_t ws_size,
                              hipStream_t stream) {
  const float* x  = (const float*)d_in[0];   // [4,4096,2048]
  const float* w1 = (const float*)d_in[1];   // [2048,256]
  const float* w2 = (const float*)d_in[2];   // [256,8192]
  const float* b2 = (const float*)d_in[3];   // [8192]
  float* out = (float*)d_out;                // [4,4096,2048]

  // workspace layout (bf16): w1t 1MB | w2t 4MB | h 8MB  (= 13MB total)
  u16* w1t = (u16*)d_ws;                     // [256][2048]
  u16* w2t = w1t + (size_t)H_DIM * D_DIM;    // [8192][256]
  u16* h   = w2t + (size_t)NFLAT * H_DIM;    // [16384][256]

  tr_cvt<<<dim3(H_DIM / 32, D_DIM / 32), 256, 0, stream>>>(w1, w1t, D_DIM, H_DIM);
  tr_cvt<<<dim3(NFLAT / 32, H_DIM / 32), 256, 0, stream>>>(w2, w2t, H_DIM, NFLAT);
  gemm1_silu<<<dim3(H_DIM / 64, M_DIM / 128), 256, 0, stream>>>(x, w1t, h);
  gemm2_conv_silu<<<dim3(D_DIM / 32, M_DIM / 128), 256, 0, stream>>>(h, w2t, b2, x, out);
}

// Round 2
// 480.297 us; speedup vs baseline: 2.5006x; 2.5006x over previous
//
#include <hip/hip_runtime.h>
#include <hip/hip_bf16.h>

typedef unsigned short u16;
typedef unsigned int   u32;
typedef __attribute__((ext_vector_type(8))) short short8;   // 8 bf16 (4 VGPRs)
typedef __attribute__((ext_vector_type(4))) float floatx4;  // MFMA acc

#define T_DIM 4096
#define D_DIM 2048
#define H_DIM 256
#define M_DIM 16384   // B*T
#define NFLAT 8192    // D*W

__device__ __forceinline__ u16 f2bf(float f) {
  union { float f; u32 u; } c; c.f = f;
  u32 x = c.u;
  x += 0x7FFFu + ((x >> 16) & 1u);   // RNE
  return (u16)(x >> 16);
}

// ---------------- transpose + fp32->bf16 convert: src[R][C] -> dst[C][R] ----
__global__ void __launch_bounds__(256) tr_cvt(const float* __restrict__ src,
                                              u16* __restrict__ dst, int R, int C) {
  __shared__ u16 tile[32][33];
  const int tx = threadIdx.x & 31;
  const int ty = threadIdx.x >> 5;        // 0..7
  const int c0 = blockIdx.x * 32;
  const int r0 = blockIdx.y * 32;
  #pragma unroll
  for (int i = ty; i < 32; i += 8)
    tile[i][tx] = f2bf(src[(size_t)(r0 + i) * C + (c0 + tx)]);
  __syncthreads();
  #pragma unroll
  for (int i = ty; i < 32; i += 8)
    dst[(size_t)(c0 + i) * R + (r0 + tx)] = tile[tx][i];
}

// ---------------- GEMM1: h = silu(x @ w1), x fp32 (inline cvt), w1t bf16 ----
// tile 128(M) x 64(N), K=2048, BK=32. block=256thr=4 waves, wave wv: 32 rows.
__global__ void __launch_bounds__(256) gemm1_silu(const float* __restrict__ X,
                                                  const u16* __restrict__ Bt,  // w1t [256][2048]
                                                  u16* __restrict__ H) {
  __shared__ __align__(16) u16 As[128][32];
  __shared__ __align__(16) u16 Bs[64][32];
  const int tid  = threadIdx.x;
  const int lane = tid & 63, l15 = lane & 15, quad = lane >> 4;
  const int wv   = tid >> 6;                 // 0..3
  const int m0   = blockIdx.y * 128;
  const int n0   = blockIdx.x * 64;
  const int K    = D_DIM;

  floatx4 acc[2][4];
  const floatx4 zf = {0.f, 0.f, 0.f, 0.f};
  #pragma unroll
  for (int i = 0; i < 2; ++i)
    #pragma unroll
    for (int j = 0; j < 4; ++j) acc[i][j] = zf;

  for (int k0 = 0; k0 < K; k0 += 32) {
    __syncthreads();
    // stage A: fp32 -> bf16, 128x32, 4 float4 per thread
    #pragma unroll
    for (int j = 0; j < 4; ++j) {
      int idx = tid + j * 256;
      int row = idx >> 3;
      int ko  = (idx & 7) * 4;
      float4 v = *(const float4*)&X[(size_t)(m0 + row) * K + k0 + ko];
      uint2 pk;
      pk.x = (u32)f2bf(v.x) | ((u32)f2bf(v.y) << 16);
      pk.y = (u32)f2bf(v.z) | ((u32)f2bf(v.w) << 16);
      *(uint2*)&As[row][ko] = pk;
    }
    // stage B (bf16): 64x32 = 256 uint4, 1 per thread
    {
      int row = tid >> 2;
      int ko  = (tid & 3) * 8;
      *(uint4*)&Bs[row][ko] = *(const uint4*)&Bt[(size_t)(n0 + row) * K + k0 + ko];
    }
    __syncthreads();
    short8 af[2], bfr[4];
    #pragma unroll
    for (int mi = 0; mi < 2; ++mi)
      af[mi] = *(const short8*)&As[wv * 32 + mi * 16 + l15][quad * 8];
    #pragma unroll
    for (int ni = 0; ni < 4; ++ni)
      bfr[ni] = *(const short8*)&Bs[ni * 16 + l15][quad * 8];
    #pragma unroll
    for (int mi = 0; mi < 2; ++mi)
      #pragma unroll
      for (int ni = 0; ni < 4; ++ni)
        acc[mi][ni] = __builtin_amdgcn_mfma_f32_16x16x32_bf16(af[mi], bfr[ni], acc[mi][ni], 0, 0, 0);
  }
  // epilogue: silu -> bf16 h
  #pragma unroll
  for (int mi = 0; mi < 2; ++mi)
    #pragma unroll
    for (int ni = 0; ni < 4; ++ni)
      #pragma unroll
      for (int r = 0; r < 4; ++r) {
        float v = acc[mi][ni][r];
        v = v / (1.f + __expf(-v));
        int row = m0 + wv * 32 + mi * 16 + quad * 4 + r;
        int col = n0 + ni * 16 + l15;
        H[(size_t)row * H_DIM + col] = f2bf(v);
      }
}

// ---- GEMM2 fused: flat = h @ w2 + b2 ; out = silu(conv(flat, x)) ----------
// tile: 128 tokens x 32 channels (=128 contiguous flat cols, n=4d+w). K=256.
// block=256thr=4 waves in 2x2; each wave 64x64 (acc[4][4] of 16x16x32 MFMA).
__global__ void __launch_bounds__(256) gemm2_conv_silu(const u16* __restrict__ Hin,   // [M][256] bf16
                                                       const u16* __restrict__ Bt,    // w2t [8192][256] bf16
                                                       const float* __restrict__ bias,// [8192] fp32
                                                       const float* __restrict__ X,   // [M][2048] fp32
                                                       float* __restrict__ Out) {     // [M][2048] fp32
  __shared__ __align__(16) u16 As[128][32];
  __shared__ __align__(16) u16 Bs[128][32];
  __shared__ __align__(16) float fl[32][132];   // +4 pad: acc-write 2-way only

  const int tid  = threadIdx.x;
  const int lane = tid & 63, l15 = lane & 15, quad = lane >> 4;
  const int wv   = tid >> 6, wy = wv >> 1, wx = wv & 1;
  const int m0   = blockIdx.y * 128;
  const int d0   = blockIdx.x * 32;
  const int n0   = d0 * 4;               // contiguous flat-column base
  const int K    = H_DIM;                // 256

  floatx4 acc[4][4];
  const floatx4 zf = {0.f, 0.f, 0.f, 0.f};
  #pragma unroll
  for (int i = 0; i < 4; ++i)
    #pragma unroll
    for (int j = 0; j < 4; ++j) acc[i][j] = zf;

  for (int k0 = 0; k0 < K; k0 += 32) {   // 8 iterations
    __syncthreads();
    #pragma unroll
    for (int j = 0; j < 2; ++j) {        // A and B: 512 uint4 each, 2 per thread
      int idx = tid + j * 256;
      int row = idx >> 2;
      int ko  = (idx & 3) * 8;
      *(uint4*)&As[row][ko] = *(const uint4*)&Hin[(size_t)(m0 + row) * K + k0 + ko];
      *(uint4*)&Bs[row][ko] = *(const uint4*)&Bt[(size_t)(n0 + row) * K + k0 + ko];
    }
    __syncthreads();
    short8 af[4], bfr[4];
    #pragma unroll
    for (int mi = 0; mi < 4; ++mi)
      af[mi] = *(const short8*)&As[wy * 64 + mi * 16 + l15][quad * 8];
    #pragma unroll
    for (int ni = 0; ni < 4; ++ni)
      bfr[ni] = *(const short8*)&Bs[wx * 64 + ni * 16 + l15][quad * 8];
    #pragma unroll
    for (int mi = 0; mi < 4; ++mi)
      #pragma unroll
      for (int ni = 0; ni < 4; ++ni)
        acc[mi][ni] = __builtin_amdgcn_mfma_f32_16x16x32_bf16(af[mi], bfr[ni], acc[mi][ni], 0, 0, 0);
  }

  const int tbase = m0 & (T_DIM - 1);    // token offset within batch (tiles never straddle)
  const int bbase = m0 - tbase;          // b * T_DIM

  // epilogue in 4 chunks of 32 rows: acc -> LDS -> (bias, conv, silu) -> Out
  // FULLY UNROLLED: mi must be a compile-time constant, otherwise acc[] is
  // dynamically indexed and the compiler demotes it to scratch (R1: 4.1 GB
  // of scratch writes, 916 us).
  #pragma unroll
  for (int mi = 0; mi < 4; ++mi) {
    __syncthreads();                      // previous chunk fully read
    #pragma unroll
    for (int ni = 0; ni < 4; ++ni)
      #pragma unroll
      for (int r = 0; r < 4; ++r)
        fl[wy * 16 + quad * 4 + r][wx * 64 + ni * 16 + l15] = acc[mi][ni][r];
    __syncthreads();
    #pragma unroll
    for (int p = 0; p < 4; ++p) {
      int i    = tid + p * 256;           // 1024 outputs: 32 rows x 32 channels
      int rowc = i >> 5;                  // 0..31
      int dl   = i & 31;
      int t_local = (rowc >> 4) * 64 + mi * 16 + (rowc & 15);
      float4 pre = *(const float4*)&fl[rowc][dl * 4];
      float4 bv  = *(const float4*)&bias[(size_t)(d0 + dl) * 4];
      float c0 = pre.x + bv.x, c1 = pre.y + bv.y, c2 = pre.z + bv.z, c3 = pre.w + bv.w;
      int tb = tbase + t_local;
      const float* xcol = &X[(size_t)(bbase + tb) * D_DIM + d0 + dl];
      // out[t] = sum_w flat[t,d,w] * x[t-3+w, d]; tap w=3 hits x[t] (always valid)
      float o = c3 * xcol[0];
      float x2 = (tb >= 1) ? xcol[-(int)D_DIM]     : 0.f;
      float x1 = (tb >= 2) ? xcol[-2 * (int)D_DIM] : 0.f;
      float x0 = (tb >= 3) ? xcol[-3 * (int)D_DIM] : 0.f;
      o += c2 * x2 + c1 * x1 + c0 * x0;
      float y = o / (1.f + __expf(-o));
      Out[(size_t)(m0 + t_local) * D_DIM + d0 + dl] = y;
    }
  }
}

extern "C" void kernel_launch(void* const* d_in, const int* in_sizes, int n_in,
                              void* d_out, int out_size, void* d_ws, size_t ws_size,
                              hipStream_t stream) {
  const float* x  = (const float*)d_in[0];   // [4,4096,2048]
  const float* w1 = (const float*)d_in[1];   // [2048,256]
  const float* w2 = (const float*)d_in[2];   // [256,8192]
  const float* b2 = (const float*)d_in[3];   // [8192]
  float* out = (float*)d_out;                // [4,4096,2048]

  // workspace layout (bf16): w1t 1MB | w2t 4MB | h 8MB  (= 13MB total)
  u16* w1t = (u16*)d_ws;                     // [256][2048]
  u16* w2t = w1t + (size_t)H_DIM * D_DIM;    // [8192][256]
  u16* h   = w2t + (size_t)NFLAT * H_DIM;    // [16384][256]

  tr_cvt<<<dim3(H_DIM / 32, D_DIM / 32), 256, 0, stream>>>(w1, w1t, D_DIM, H_DIM);
  tr_cvt<<<dim3(NFLAT / 32, H_DIM / 32), 256, 0, stream>>>(w2, w2t, H_DIM, NFLAT);
  gemm1_silu<<<dim3(H_DIM / 64, M_DIM / 128), 256, 0, stream>>>(x, w1t, h);
  gemm2_conv_silu<<<dim3(D_DIM / 32, M_DIM / 128), 256, 0, stream>>>(h, w2t, b2, x, out);
}

// Round 3
// 465.190 us; speedup vs baseline: 2.5818x; 1.0325x over previous
//
#include <hip/hip_runtime.h>
#include <hip/hip_bf16.h>

typedef unsigned short u16;
typedef unsigned int   u32;
typedef __attribute__((ext_vector_type(8))) short short8;   // 8 bf16 (4 VGPRs)
typedef __attribute__((ext_vector_type(4))) float floatx4;  // MFMA acc

#define T_DIM 4096
#define D_DIM 2048
#define H_DIM 256
#define M_DIM 16384   // B*T
#define NFLAT 8192    // D*W

__device__ __forceinline__ u16 f2bf(float f) {
  union { float f; u32 u; } c; c.f = f;
  u32 x = c.u;
  x += 0x7FFFu + ((x >> 16) & 1u);   // RNE
  return (u16)(x >> 16);
}

// async global->LDS, 16B per lane. LDS dest = wave-uniform base + lane*16.
__device__ __forceinline__ void glds16(const void* g, void* l) {
  __builtin_amdgcn_global_load_lds(
      (const __attribute__((address_space(1))) void*)g,
      (__attribute__((address_space(3))) void*)l, 16, 0, 0);
}

// ---------------- X fp32 -> bf16, elementwise, 8 elems/thread ---------------
__global__ void __launch_bounds__(256) xcvt(const float* __restrict__ X,
                                            u16* __restrict__ Xb) {
  size_t base = ((size_t)blockIdx.x * 256 + threadIdx.x) * 8;
  float4 a = *(const float4*)&X[base];
  float4 b = *(const float4*)&X[base + 4];
  uint4 o;
  o.x = (u32)f2bf(a.x) | ((u32)f2bf(a.y) << 16);
  o.y = (u32)f2bf(a.z) | ((u32)f2bf(a.w) << 16);
  o.z = (u32)f2bf(b.x) | ((u32)f2bf(b.y) << 16);
  o.w = (u32)f2bf(b.z) | ((u32)f2bf(b.w) << 16);
  *(uint4*)&Xb[base] = o;
}

// ---------------- transpose + fp32->bf16 convert: src[R][C] -> dst[C][R] ----
__global__ void __launch_bounds__(256) tr_cvt(const float* __restrict__ src,
                                              u16* __restrict__ dst, int R, int C) {
  __shared__ u16 tile[32][33];
  const int tx = threadIdx.x & 31;
  const int ty = threadIdx.x >> 5;        // 0..7
  const int c0 = blockIdx.x * 32;
  const int r0 = blockIdx.y * 32;
  #pragma unroll
  for (int i = ty; i < 32; i += 8)
    tile[i][tx] = f2bf(src[(size_t)(r0 + i) * C + (c0 + tx)]);
  __syncthreads();
  #pragma unroll
  for (int i = ty; i < 32; i += 8)
    dst[(size_t)(c0 + i) * R + (r0 + tx)] = tile[tx][i];
}

// ---------------- GEMM1: h = silu(xb @ w1), all bf16, glds staging ----------
// tile 64(M) x 256(N = full H), BK=32, 64 k-iters. grid = M/64 = 256 blocks.
// 4 waves side-by-side in N; each wave 64x64 -> acc[4][4]. xb read ONCE.
__global__ void __launch_bounds__(256) gemm1_silu(const u16* __restrict__ Xb,  // [M][2048]
                                                  const u16* __restrict__ Bt,  // w1t [256][2048]
                                                  u16* __restrict__ H) {       // [M][256]
  __shared__ __align__(16) u16 As[64][32];    // 4 KB  = 4 x 1KB wave chunks
  __shared__ __align__(16) u16 Bs[256][32];   // 16 KB = 16 chunks
  const int tid  = threadIdx.x;
  const int lane = tid & 63, l15 = lane & 15, quad = lane >> 4;
  const int wv   = tid >> 6;                  // 0..3
  const int m0   = blockIdx.x * 64;

  floatx4 acc[4][4];
  const floatx4 zf = {0.f, 0.f, 0.f, 0.f};
  #pragma unroll
  for (int i = 0; i < 4; ++i)
    #pragma unroll
    for (int j = 0; j < 4; ++j) acc[i][j] = zf;

  for (int k0 = 0; k0 < D_DIM; k0 += 32) {
    __syncthreads();
    {  // As: 1 chunk per wave (slot -> row = slot>>2, ko = (slot&3)*8)
      int slot = wv * 64 + lane;
      glds16(&Xb[(size_t)(m0 + (slot >> 2)) * D_DIM + k0 + (slot & 3) * 8],
             (char*)As + wv * 1024);
    }
    #pragma unroll
    for (int c = 0; c < 4; ++c) {  // Bs: 4 chunks per wave
      int ch   = c * 4 + wv;
      int slot = ch * 64 + lane;
      glds16(&Bt[(size_t)(slot >> 2) * D_DIM + k0 + (slot & 3) * 8],
             (char*)Bs + ch * 1024);
    }
    __syncthreads();
    short8 af[4], bfr[4];
    #pragma unroll
    for (int mi = 0; mi < 4; ++mi)
      af[mi] = *(const short8*)&As[mi * 16 + l15][quad * 8];
    #pragma unroll
    for (int ni = 0; ni < 4; ++ni)
      bfr[ni] = *(const short8*)&Bs[wv * 64 + ni * 16 + l15][quad * 8];
    #pragma unroll
    for (int mi = 0; mi < 4; ++mi)
      #pragma unroll
      for (int ni = 0; ni < 4; ++ni)
        acc[mi][ni] = __builtin_amdgcn_mfma_f32_16x16x32_bf16(af[mi], bfr[ni], acc[mi][ni], 0, 0, 0);
  }
  // epilogue: silu -> bf16 h
  #pragma unroll
  for (int mi = 0; mi < 4; ++mi)
    #pragma unroll
    for (int ni = 0; ni < 4; ++ni)
      #pragma unroll
      for (int r = 0; r < 4; ++r) {
        float v = acc[mi][ni][r];
        v = v / (1.f + __expf(-v));
        int row = m0 + mi * 16 + quad * 4 + r;
        int col = wv * 64 + ni * 16 + l15;
        H[(size_t)row * H_DIM + col] = f2bf(v);
      }
}

// ------- GEMM1 fallback (R2 version, fp32 X inline-cvt) if ws too small -----
__global__ void __launch_bounds__(256) gemm1_silu_f32(const float* __restrict__ X,
                                                      const u16* __restrict__ Bt,
                                                      u16* __restrict__ H) {
  __shared__ __align__(16) u16 As[128][32];
  __shared__ __align__(16) u16 Bs[64][32];
  const int tid  = threadIdx.x;
  const int lane = tid & 63, l15 = lane & 15, quad = lane >> 4;
  const int wv   = tid >> 6;
  const int m0   = blockIdx.y * 128;
  const int n0   = blockIdx.x * 64;
  const int K    = D_DIM;
  floatx4 acc[2][4];
  const floatx4 zf = {0.f, 0.f, 0.f, 0.f};
  #pragma unroll
  for (int i = 0; i < 2; ++i)
    #pragma unroll
    for (int j = 0; j < 4; ++j) acc[i][j] = zf;
  for (int k0 = 0; k0 < K; k0 += 32) {
    __syncthreads();
    #pragma unroll
    for (int j = 0; j < 4; ++j) {
      int idx = tid + j * 256;
      int row = idx >> 3;
      int ko  = (idx & 7) * 4;
      float4 v = *(const float4*)&X[(size_t)(m0 + row) * K + k0 + ko];
      uint2 pk;
      pk.x = (u32)f2bf(v.x) | ((u32)f2bf(v.y) << 16);
      pk.y = (u32)f2bf(v.z) | ((u32)f2bf(v.w) << 16);
      *(uint2*)&As[row][ko] = pk;
    }
    {
      int row = tid >> 2;
      int ko  = (tid & 3) * 8;
      *(uint4*)&Bs[row][ko] = *(const uint4*)&Bt[(size_t)(n0 + row) * K + k0 + ko];
    }
    __syncthreads();
    short8 af[2], bfr[4];
    #pragma unroll
    for (int mi = 0; mi < 2; ++mi)
      af[mi] = *(const short8*)&As[wv * 32 + mi * 16 + l15][quad * 8];
    #pragma unroll
    for (int ni = 0; ni < 4; ++ni)
      bfr[ni] = *(const short8*)&Bs[ni * 16 + l15][quad * 8];
    #pragma unroll
    for (int mi = 0; mi < 2; ++mi)
      #pragma unroll
      for (int ni = 0; ni < 4; ++ni)
        acc[mi][ni] = __builtin_amdgcn_mfma_f32_16x16x32_bf16(af[mi], bfr[ni], acc[mi][ni], 0, 0, 0);
  }
  #pragma unroll
  for (int mi = 0; mi < 2; ++mi)
    #pragma unroll
    for (int ni = 0; ni < 4; ++ni)
      #pragma unroll
      for (int r = 0; r < 4; ++r) {
        float v = acc[mi][ni][r];
        v = v / (1.f + __expf(-v));
        int row = m0 + wv * 32 + mi * 16 + quad * 4 + r;
        int col = n0 + ni * 16 + l15;
        H[(size_t)row * H_DIM + col] = f2bf(v);
      }
}

// ---- GEMM2 fused: flat = h @ w2 + b2 ; out = silu(conv(flat, x)) ----------
// tile 128 tokens x 32 channels (=128 contiguous flat cols). K=256, 8 iters.
// glds staging; fl overlays As/Bs (dead after K-loop) -> LDS 16.9 KB total.
__global__ void __launch_bounds__(256) gemm2_conv_silu(const u16* __restrict__ Hin,   // [M][256] bf16
                                                       const u16* __restrict__ Bt,    // w2t [8192][256] bf16
                                                       const float* __restrict__ bias,// [8192] fp32
                                                       const float* __restrict__ X,   // [M][2048] fp32
                                                       float* __restrict__ Out) {     // [M][2048] fp32
  __shared__ __align__(16) char smem[16896];
  u16 (*As)[32] = (u16(*)[32])smem;              // 8 KB, chunks 0..7
  u16 (*Bs)[32] = (u16(*)[32])(smem + 8192);     // 8 KB, chunks 0..7
  float (*fl)[132] = (float(*)[132])smem;        // 16.9 KB overlay (epilogue)

  const int tid  = threadIdx.x;
  const int lane = tid & 63, l15 = lane & 15, quad = lane >> 4;
  const int wv   = tid >> 6, wy = wv >> 1, wx = wv & 1;
  const int m0   = blockIdx.y * 128;
  const int d0   = blockIdx.x * 32;
  const int n0   = d0 * 4;               // contiguous flat-column base

  floatx4 acc[4][4];
  const floatx4 zf = {0.f, 0.f, 0.f, 0.f};
  #pragma unroll
  for (int i = 0; i < 4; ++i)
    #pragma unroll
    for (int j = 0; j < 4; ++j) acc[i][j] = zf;

  for (int k0 = 0; k0 < H_DIM; k0 += 32) {   // 8 iterations
    __syncthreads();
    #pragma unroll
    for (int c = 0; c < 2; ++c) {
      int ch   = c * 4 + wv;
      int slot = ch * 64 + lane;
      int row  = slot >> 2, ko = (slot & 3) * 8;
      glds16(&Hin[(size_t)(m0 + row) * H_DIM + k0 + ko], smem + ch * 1024);
      glds16(&Bt[(size_t)(n0 + row) * H_DIM + k0 + ko], smem + 8192 + ch * 1024);
    }
    __syncthreads();
    short8 af[4], bfr[4];
    #pragma unroll
    for (int mi = 0; mi < 4; ++mi)
      af[mi] = *(const short8*)&As[wy * 64 + mi * 16 + l15][quad * 8];
    #pragma unroll
    for (int ni = 0; ni < 4; ++ni)
      bfr[ni] = *(const short8*)&Bs[wx * 64 + ni * 16 + l15][quad * 8];
    #pragma unroll
    for (int mi = 0; mi < 4; ++mi)
      #pragma unroll
      for (int ni = 0; ni < 4; ++ni)
        acc[mi][ni] = __builtin_amdgcn_mfma_f32_16x16x32_bf16(af[mi], bfr[ni], acc[mi][ni], 0, 0, 0);
  }

  const int tbase = m0 & (T_DIM - 1);    // token offset within batch (tiles never straddle)
  const int bbase = m0 - tbase;          // b * T_DIM

  // epilogue in 4 chunks of 32 rows. mi MUST stay compile-time (R1: scratch).
  #pragma unroll
  for (int mi = 0; mi < 4; ++mi) {
    __syncthreads();                      // K-loop reads / previous chunk done
    #pragma unroll
    for (int ni = 0; ni < 4; ++ni)
      #pragma unroll
      for (int r = 0; r < 4; ++r)
        fl[wy * 16 + quad * 4 + r][wx * 64 + ni * 16 + l15] = acc[mi][ni][r];
    __syncthreads();
    #pragma unroll
    for (int p = 0; p < 4; ++p) {
      int i    = tid + p * 256;           // 1024 outputs: 32 rows x 32 channels
      int rowc = i >> 5;                  // 0..31
      int dl   = i & 31;
      int t_local = (rowc >> 4) * 64 + mi * 16 + (rowc & 15);
      float4 pre = *(const float4*)&fl[rowc][dl * 4];
      float4 bv  = *(const float4*)&bias[(size_t)(d0 + dl) * 4];
      float c0 = pre.x + bv.x, c1 = pre.y + bv.y, c2 = pre.z + bv.z, c3 = pre.w + bv.w;
      int tb = tbase + t_local;
      const float* xcol = &X[(size_t)(bbase + tb) * D_DIM + d0 + dl];
      float o = c3 * xcol[0];
      float x2 = (tb >= 1) ? xcol[-(int)D_DIM]     : 0.f;
      float x1 = (tb >= 2) ? xcol[-2 * (int)D_DIM] : 0.f;
      float x0 = (tb >= 3) ? xcol[-3 * (int)D_DIM] : 0.f;
      o += c2 * x2 + c1 * x1 + c0 * x0;
      float y = o / (1.f + __expf(-o));
      Out[(size_t)(m0 + t_local) * D_DIM + d0 + dl] = y;
    }
  }
}

extern "C" void kernel_launch(void* const* d_in, const int* in_sizes, int n_in,
                              void* d_out, int out_size, void* d_ws, size_t ws_size,
                              hipStream_t stream) {
  const float* x  = (const float*)d_in[0];   // [4,4096,2048]
  const float* w1 = (const float*)d_in[1];   // [2048,256]
  const float* w2 = (const float*)d_in[2];   // [256,8192]
  const float* b2 = (const float*)d_in[3];   // [8192]
  float* out = (float*)d_out;                // [4,4096,2048]

  // ws layout (u16 elems): w1t 512K | w2t 2M | h 4M | xb 32M  (= ~80.7 MB)
  u16* w1t = (u16*)d_ws;                     // [256][2048]
  u16* w2t = w1t + (size_t)H_DIM * D_DIM;    // [8192][256]
  u16* h   = w2t + (size_t)NFLAT * H_DIM;    // [16384][256]
  u16* xb  = h   + (size_t)M_DIM * H_DIM;    // [16384][2048]
  const size_t need = ((size_t)H_DIM * D_DIM + (size_t)NFLAT * H_DIM +
                       (size_t)M_DIM * H_DIM + (size_t)M_DIM * D_DIM) * sizeof(u16);

  tr_cvt<<<dim3(H_DIM / 32, D_DIM / 32), 256, 0, stream>>>(w1, w1t, D_DIM, H_DIM);
  tr_cvt<<<dim3(NFLAT / 32, H_DIM / 32), 256, 0, stream>>>(w2, w2t, H_DIM, NFLAT);
  if (ws_size >= need) {
    xcvt<<<(M_DIM * (size_t)D_DIM) / (256 * 8), 256, 0, stream>>>(x, xb);
    gemm1_silu<<<M_DIM / 64, 256, 0, stream>>>(xb, w1t, h);
  } else {
    gemm1_silu_f32<<<dim3(H_DIM / 64, M_DIM / 128), 256, 0, stream>>>(x, w1t, h);
  }
  gemm2_conv_silu<<<dim3(D_DIM / 32, M_DIM / 128), 256, 0, stream>>>(h, w2t, b2, x, out);
}